// Round 7
// baseline (152.160 us; speedup 1.0000x reference)
//
#include <hip/hip_runtime.h>
#include <math.h>

#define IN_F   1024
#define OUT_F  1024
#define TASK_D 256
#define RANK   8
#define HID    64
// SCALING = ALPHA / RANK = 1.0 (identity)

__device__ __forceinline__ float gelu_exact(float v) {
    return 0.5f * v * (1.0f + erff(v * 0.70710678118654752f));
}

// ---------------------------------------------------------------------------
// Kernel 1: generate LoRA tables (512 blocks x 256 threads).
// Blocks 0..255 -> gen_a, 256..511 -> gen_b. Each block: redundant h[4][64],
// then 32 W2 rows/block, 8 threads/row, 3-stage shuffle reduce.
//   vec_a_t : [4][RANK][OUT_F]  (TRANSPOSED: a_t[t][r][o] = a[t][o][r])
//   vec_b   : [4][RANK][IN_F]   (natural Wb2 row order)
// ---------------------------------------------------------------------------
__global__ __launch_bounds__(256) void gen_kernel(
    const float* __restrict__ task_emb,
    const float* __restrict__ Wa1, const float* __restrict__ ba1,
    const float* __restrict__ Wa2, const float* __restrict__ ba2,
    const float* __restrict__ Wb1, const float* __restrict__ bb1,
    const float* __restrict__ Wb2, const float* __restrict__ bb2,
    float* __restrict__ vec_a_t, float* __restrict__ vec_b)
{
    const int gen = blockIdx.x >> 8;             // 0 -> a, 1 -> b
    const int blk = blockIdx.x & 255;            // 256 blocks per generator
    const float* __restrict__ W1 = gen ? Wb1 : Wa1;
    const float* __restrict__ b1 = gen ? bb1 : ba1;
    const float* __restrict__ W2 = gen ? Wb2 : Wa2;
    const float* __restrict__ b2 = gen ? bb2 : ba2;

    __shared__ float hs[4][HID];
    {
        const int j = threadIdx.x >> 2;          // hidden unit 0..63
        const int t = threadIdx.x & 3;           // task 0..3
        const float4* te = (const float4*)(task_emb + t * TASK_D);
        const float4* w  = (const float4*)(W1 + j * TASK_D);
        float acc = 0.f;
        #pragma unroll
        for (int d = 0; d < TASK_D / 4; ++d) {
            float4 a = te[d], b = w[d];
            acc += a.x * b.x + a.y * b.y + a.z * b.z + a.w * b.w;
        }
        hs[t][j] = gelu_exact(acc + b1[j]);
    }
    __syncthreads();

    const int lrow = threadIdx.x >> 3;           // 0..31  (W2 row within block)
    const int q    = threadIdx.x & 7;            // eighth of the 64 hidden dims
    const int o    = blk * 32 + lrow;            // W2 row 0..8191

    const float4* w2 = (const float4*)(W2 + (size_t)o * HID + q * 8);
    float acc0 = 0.f, acc1 = 0.f, acc2 = 0.f, acc3 = 0.f;
    #pragma unroll
    for (int k = 0; k < 2; ++k) {
        float4 w = w2[k];
        const int kb = q * 8 + k * 4;
        acc0 += hs[0][kb] * w.x + hs[0][kb+1] * w.y + hs[0][kb+2] * w.z + hs[0][kb+3] * w.w;
        acc1 += hs[1][kb] * w.x + hs[1][kb+1] * w.y + hs[1][kb+2] * w.z + hs[1][kb+3] * w.w;
        acc2 += hs[2][kb] * w.x + hs[2][kb+1] * w.y + hs[2][kb+2] * w.z + hs[2][kb+3] * w.w;
        acc3 += hs[3][kb] * w.x + hs[3][kb+1] * w.y + hs[3][kb+2] * w.z + hs[3][kb+3] * w.w;
    }
    #pragma unroll
    for (int off = 1; off <= 4; off <<= 1) {
        acc0 += __shfl_xor(acc0, off, 64);
        acc1 += __shfl_xor(acc1, off, 64);
        acc2 += __shfl_xor(acc2, off, 64);
        acc3 += __shfl_xor(acc3, off, 64);
    }
    if (q == 0) {
        const float bb = b2[o];
        float v[4] = { acc0 + bb, acc1 + bb, acc2 + bb, acc3 + bb };
        if (gen == 0) {
            const int oo = o >> 3, r = o & 7;    // vec_a row o -> (out oo, rank r)
            #pragma unroll
            for (int t = 0; t < 4; ++t)
                vec_a_t[t * (RANK * OUT_F) + r * OUT_F + oo] = v[t];
        } else {
            #pragma unroll
            for (int t = 0; t < 4; ++t)
                vec_b[t * (RANK * IN_F) + o] = v[t];
        }
    }
}

// ---------------------------------------------------------------------------
// Kernel 2 (v7): fused apply, minimal VMEM/row (~20 lane-instr/row).
// 1024 blocks x 256 thr, 8 rows/block, task-pure blocks; 4 blocks/CU
// (LDS 32.3 KB, VGPR<=128 via __launch_bounds__(256,4)) -> grid exactly
// co-resident at 16 waves/CU.
//   stage : b-table -> LDS (8 float4/thread, coalesced; v1's proven piece)
//   af    : 8 a-fragments/thread from global L1, loaded ONCE per block
//           (1 table-load/row), issued BEFORE the barrier to overlap stage.
//   phase1: 2 rows/wave, x loads hoisted for both rows (8 in flight),
//           b from LDS (0 conflicts in v1), 6-stage butterfly, tmp->LDS.
//   phase2: column-per-thread (zero cross-lane), bo hoisted 4-deep.
// ---------------------------------------------------------------------------
__global__ __launch_bounds__(256, 4) void apply_kernel(
    const float* __restrict__ x, const float* __restrict__ base_out,
    const float* __restrict__ vec_a_t, const float* __restrict__ vec_b,
    float* __restrict__ out, int blocks_per_task)
{
    const int t    = blockIdx.x / blocks_per_task;   // task 0..3
    const int g    = blockIdx.x % blocks_per_task;   // group within task
    const int wave = threadIdx.x >> 6;
    const int ln   = threadIdx.x & 63;

    __shared__ float bs[RANK * IN_F];                // 32 KB
    __shared__ float tmps[8][RANK];                  // 256 B

    // ---- stage b-table to LDS --------------------------------------------
    {
        const float4* __restrict__ src =
            (const float4*)(vec_b + (size_t)t * (RANK * IN_F));
        float4* dst = (float4*)bs;
        #pragma unroll
        for (int i = 0; i < 8; ++i)
            dst[threadIdx.x + 256 * i] = src[threadIdx.x + 256 * i];
    }

    // ---- a-fragments: once per block, overlapped with stage --------------
    const int o = threadIdx.x * 4;
    const float* __restrict__ at = vec_a_t + (size_t)t * (RANK * OUT_F);
    float4 af[RANK];
    #pragma unroll
    for (int r = 0; r < RANK; ++r)
        af[r] = *(const float4*)(at + r * OUT_F + o);

    __syncthreads();

    // ---- phase 1: 2 rows per wave, x hoisted for both ---------------------
    {
        const int j0 = g * 8 + wave * 2;             // within-task row index
        float4 xv[2][4];
        #pragma unroll
        for (int i = 0; i < 2; ++i) {
            const int row = t + 4 * (j0 + i);
            const float* __restrict__ xr = x + (size_t)row * IN_F;
            #pragma unroll
            for (int c = 0; c < 4; ++c)
                xv[i][c] = *(const float4*)(xr + c * 256 + ln * 4);
        }
        #pragma unroll
        for (int i = 0; i < 2; ++i) {
            float acc[RANK];
            #pragma unroll
            for (int r = 0; r < RANK; ++r) acc[r] = 0.f;
            #pragma unroll
            for (int c = 0; c < 4; ++c) {
                const int k = c * 256 + ln * 4;
                #pragma unroll
                for (int r = 0; r < RANK; ++r) {
                    const float4 bv = *(const float4*)(bs + r * IN_F + k);
                    acc[r] += xv[i][c].x * bv.x + xv[i][c].y * bv.y
                            + xv[i][c].z * bv.z + xv[i][c].w * bv.w;
                }
            }
            #pragma unroll
            for (int off = 1; off <= 32; off <<= 1) {
                #pragma unroll
                for (int r = 0; r < RANK; ++r)
                    acc[r] += __shfl_xor(acc[r], off, 64);
            }
            if (ln == 0) {
                #pragma unroll
                for (int r = 0; r < RANK; ++r)
                    tmps[wave * 2 + i][r] = acc[r];  // static indices
            }
        }
    }
    __syncthreads();

    // ---- phase 2: column-per-thread across all 8 rows ---------------------
    #pragma unroll
    for (int ii = 0; ii < 2; ++ii) {
        float4 bo[4];
        #pragma unroll
        for (int i = 0; i < 4; ++i) {
            const int row = t + 4 * (g * 8 + ii * 4 + i);
            bo[i] = *(const float4*)(base_out + (size_t)row * OUT_F + o);
        }
        #pragma unroll
        for (int i = 0; i < 4; ++i) {
            const int lrow = ii * 4 + i;
            const int row  = t + 4 * (g * 8 + lrow);
            const float4 t0 = *(const float4*)&tmps[lrow][0];
            const float4 t1 = *(const float4*)&tmps[lrow][4];
            const float s[RANK] = { t0.x, t0.y, t0.z, t0.w,
                                    t1.x, t1.y, t1.z, t1.w };
            float4 rv = bo[i];
            #pragma unroll
            for (int r = 0; r < RANK; ++r) {
                rv.x += s[r] * af[r].x;
                rv.y += s[r] * af[r].y;
                rv.z += s[r] * af[r].z;
                rv.w += s[r] * af[r].w;
            }
            *(float4*)(out + (size_t)row * OUT_F + o) = rv;
        }
    }
}

extern "C" void kernel_launch(void* const* d_in, const int* in_sizes, int n_in,
                              void* d_out, int out_size, void* d_ws, size_t ws_size,
                              hipStream_t stream) {
    const float* x        = (const float*)d_in[0];
    const float* base_out = (const float*)d_in[1];
    const float* task_emb = (const float*)d_in[2];
    const float* Wa1      = (const float*)d_in[3];
    const float* ba1      = (const float*)d_in[4];
    const float* Wa2      = (const float*)d_in[5];
    const float* ba2      = (const float*)d_in[6];
    const float* Wb1      = (const float*)d_in[7];
    const float* bb1      = (const float*)d_in[8];
    const float* Wb2      = (const float*)d_in[9];
    const float* bb2      = (const float*)d_in[10];
    float* out = (float*)d_out;

    float* vec_a_t = (float*)d_ws;                        // 4*8192 floats
    float* vec_b   = vec_a_t + 4 * RANK * OUT_F;          // 4*8192 floats

    const int b_eff = in_sizes[0] / IN_F;                 // 8192

    gen_kernel<<<512, 256, 0, stream>>>(task_emb, Wa1, ba1, Wa2, ba2,
                                        Wb1, bb1, Wb2, bb2, vec_a_t, vec_b);

    const int nblk = b_eff / 8;                           // 1024 blocks, 8 rows each
    apply_kernel<<<nblk, 256, 0, stream>>>(x, base_out, vec_a_t, vec_b, out,
                                           nblk / 4);
}

// Round 8
// 139.552 us; speedup vs baseline: 1.0904x; 1.0904x over previous
//
#include <hip/hip_runtime.h>
#include <math.h>

#define IN_F   1024
#define OUT_F  1024
#define TASK_D 256
#define RANK   8
#define HID    64
// SCALING = ALPHA / RANK = 1.0 (identity)

__device__ __forceinline__ float gelu_exact(float v) {
    return 0.5f * v * (1.0f + erff(v * 0.70710678118654752f));
}

// ---------------------------------------------------------------------------
// Kernel 1: generate LoRA tables for all 4 tasks.
//   vec_a_t : [4][RANK][OUT_F]  (TRANSPOSED: a_t[t][r][o] = a[t][o][r])
//   vec_b   : [4][RANK][IN_F]   (natural Wb2 row order)
// Grid: 256 blocks x 256 threads. Blocks 0..127 -> gen_a, 128..255 -> gen_b.
// Each block: redundantly computes h[4][64] (cheap), then 4 threads per W2
// row (64 rows/block) each dot 16 of the 64 hidden dims, 2-stage shuffle
// reduce, lane q==0 writes the 4 task values.
// ---------------------------------------------------------------------------
__global__ __launch_bounds__(256) void gen_kernel(
    const float* __restrict__ task_emb,
    const float* __restrict__ Wa1, const float* __restrict__ ba1,
    const float* __restrict__ Wa2, const float* __restrict__ ba2,
    const float* __restrict__ Wb1, const float* __restrict__ bb1,
    const float* __restrict__ Wb2, const float* __restrict__ bb2,
    float* __restrict__ vec_a_t, float* __restrict__ vec_b)
{
    const int gen = blockIdx.x >> 7;             // 0 -> a, 1 -> b
    const int blk = blockIdx.x & 127;
    const float* __restrict__ W1 = gen ? Wb1 : Wa1;
    const float* __restrict__ b1 = gen ? bb1 : ba1;
    const float* __restrict__ W2 = gen ? Wb2 : Wa2;
    const float* __restrict__ b2 = gen ? bb2 : ba2;

    __shared__ float hs[4][HID];
    {
        const int j = threadIdx.x >> 2;          // hidden unit 0..63
        const int t = threadIdx.x & 3;           // task 0..3
        const float4* te = (const float4*)(task_emb + t * TASK_D);
        const float4* w  = (const float4*)(W1 + j * TASK_D);
        float acc = 0.f;
        #pragma unroll
        for (int d = 0; d < TASK_D / 4; ++d) {
            float4 a = te[d], b = w[d];
            acc += a.x * b.x + a.y * b.y + a.z * b.z + a.w * b.w;
        }
        hs[t][j] = gelu_exact(acc + b1[j]);
    }
    __syncthreads();

    const int lrow = threadIdx.x >> 2;           // 0..63  (W2 row within block)
    const int q    = threadIdx.x & 3;            // quarter of the 64 hidden dims
    const int o    = blk * 64 + lrow;            // W2 row 0..8191

    const float4* w2 = (const float4*)(W2 + (size_t)o * HID + q * 16);
    float acc0 = 0.f, acc1 = 0.f, acc2 = 0.f, acc3 = 0.f;
    #pragma unroll
    for (int k = 0; k < 4; ++k) {
        float4 w = w2[k];
        const int kb = q * 16 + k * 4;
        acc0 += hs[0][kb] * w.x + hs[0][kb+1] * w.y + hs[0][kb+2] * w.z + hs[0][kb+3] * w.w;
        acc1 += hs[1][kb] * w.x + hs[1][kb+1] * w.y + hs[1][kb+2] * w.z + hs[1][kb+3] * w.w;
        acc2 += hs[2][kb] * w.x + hs[2][kb+1] * w.y + hs[2][kb+2] * w.z + hs[2][kb+3] * w.w;
        acc3 += hs[3][kb] * w.x + hs[3][kb+1] * w.y + hs[3][kb+2] * w.z + hs[3][kb+3] * w.w;
    }
    #pragma unroll
    for (int off = 1; off <= 2; off <<= 1) {
        acc0 += __shfl_xor(acc0, off, 64);
        acc1 += __shfl_xor(acc1, off, 64);
        acc2 += __shfl_xor(acc2, off, 64);
        acc3 += __shfl_xor(acc3, off, 64);
    }
    if (q == 0) {
        const float bb = b2[o];
        float v[4] = { acc0 + bb, acc1 + bb, acc2 + bb, acc3 + bb };
        if (gen == 0) {
            const int oo = o >> 3, r = o & 7;    // vec_a row o -> (out oo, rank r)
            #pragma unroll
            for (int t = 0; t < 4; ++t)
                vec_a_t[t * (RANK * OUT_F) + r * OUT_F + oo] = v[t];
        } else {
            #pragma unroll
            for (int t = 0; t < 4; ++t)
                vec_b[t * (RANK * IN_F) + o] = v[t];
        }
    }
}

// ---------------------------------------------------------------------------
// Kernel 2: fused LoRA apply. One task per block; vec_b[t] staged in LDS.
// Grid = b_eff/8 blocks x 256 threads (4 waves); each wave handles 2 rows.
//   phase 1: tmp[i][r] = sum_k x[row,k]*b[t,r,k]   (LDS b, butterfly reduce)
//   phase 2: out[row,o] = base_out[row,o] + sum_r tmp[i][r]*a_t[t][r][o]
// a-fragments (registers, coalesced float4 from L2) amortized over both rows.
// ---------------------------------------------------------------------------
__global__ __launch_bounds__(256) void apply_kernel(
    const float* __restrict__ x, const float* __restrict__ base_out,
    const float* __restrict__ vec_a_t, const float* __restrict__ vec_b,
    float* __restrict__ out)
{
    const int t    = blockIdx.x & 3;             // task
    const int g    = blockIdx.x >> 2;            // group within task
    const int wave = threadIdx.x >> 6;
    const int lane = threadIdx.x & 63;

    __shared__ float bs[RANK * IN_F];            // 32 KB
    {
        const float4* src = (const float4*)(vec_b + (size_t)t * (RANK * IN_F));
        float4* dst = (float4*)bs;
        #pragma unroll
        for (int i = 0; i < 8; ++i)
            dst[threadIdx.x + 256 * i] = src[threadIdx.x + 256 * i];
    }
    __syncthreads();

    const int jbase = g * 8 + wave * 2;          // row index / 4
    float tmp[2][RANK];

    #pragma unroll
    for (int i = 0; i < 2; ++i) {
        const int row = t + 4 * (jbase + i);
        const float* __restrict__ xr = x + (size_t)row * IN_F;
        float4 xv[4];
        #pragma unroll
        for (int c = 0; c < 4; ++c)
            xv[c] = *(const float4*)(xr + c * 256 + lane * 4);

        float acc[RANK];
        #pragma unroll
        for (int r = 0; r < RANK; ++r) acc[r] = 0.f;
        #pragma unroll
        for (int c = 0; c < 4; ++c) {
            const int k = c * 256 + lane * 4;
            #pragma unroll
            for (int r = 0; r < RANK; ++r) {
                const float4 bv = *(const float4*)(bs + r * IN_F + k);
                acc[r] += xv[c].x * bv.x + xv[c].y * bv.y + xv[c].z * bv.z + xv[c].w * bv.w;
            }
        }
        #pragma unroll
        for (int off = 32; off > 0; off >>= 1) {
            #pragma unroll
            for (int r = 0; r < RANK; ++r)
                acc[r] += __shfl_xor(acc[r], off, 64);
        }
        #pragma unroll
        for (int r = 0; r < RANK; ++r) tmp[i][r] = acc[r];
    }

    const float* __restrict__ at = vec_a_t + (size_t)t * (RANK * OUT_F);
    #pragma unroll
    for (int c = 0; c < 4; ++c) {
        const int o = c * 256 + lane * 4;
        float4 af[RANK];
        #pragma unroll
        for (int r = 0; r < RANK; ++r)
            af[r] = *(const float4*)(at + r * OUT_F + o);
        #pragma unroll
        for (int i = 0; i < 2; ++i) {
            const int row = t + 4 * (jbase + i);
            const float4 bo = *(const float4*)(base_out + (size_t)row * OUT_F + o);
            float4 rv;
            rv.x = bo.x; rv.y = bo.y; rv.z = bo.z; rv.w = bo.w;
            #pragma unroll
            for (int r = 0; r < RANK; ++r) {
                rv.x += tmp[i][r] * af[r].x;
                rv.y += tmp[i][r] * af[r].y;
                rv.z += tmp[i][r] * af[r].z;
                rv.w += tmp[i][r] * af[r].w;
            }
            *(float4*)(out + (size_t)row * OUT_F + o) = rv;
        }
    }
}

extern "C" void kernel_launch(void* const* d_in, const int* in_sizes, int n_in,
                              void* d_out, int out_size, void* d_ws, size_t ws_size,
                              hipStream_t stream) {
    const float* x        = (const float*)d_in[0];
    const float* base_out = (const float*)d_in[1];
    const float* task_emb = (const float*)d_in[2];
    const float* Wa1      = (const float*)d_in[3];
    const float* ba1      = (const float*)d_in[4];
    const float* Wa2      = (const float*)d_in[5];
    const float* ba2      = (const float*)d_in[6];
    const float* Wb1      = (const float*)d_in[7];
    const float* bb1      = (const float*)d_in[8];
    const float* Wb2      = (const float*)d_in[9];
    const float* bb2      = (const float*)d_in[10];
    float* out = (float*)d_out;

    float* vec_a_t = (float*)d_ws;                        // 4*8192 floats
    float* vec_b   = vec_a_t + 4 * RANK * OUT_F;          // 4*8192 floats

    const int b_eff = in_sizes[0] / IN_F;                 // 8192

    gen_kernel<<<256, 256, 0, stream>>>(task_emb, Wa1, ba1, Wa2, ba2,
                                        Wb1, bb1, Wb2, bb2, vec_a_t, vec_b);
    apply_kernel<<<b_eff / 8, 256, 0, stream>>>(x, base_out, vec_a_t, vec_b, out);
}